// Round 1
// baseline (143.184 us; speedup 1.0000x reference)
//
#include <hip/hip_runtime.h>

#define LN_EPS 1e-5f

constexpr int kH = 768;          // hidden dim (asserted via in_sizes at launch)
constexpr int kBlock = 256;      // threads per block
constexpr int kPer = kH / kBlock; // 3 elements per thread

// One block per output row (b,t).
// Does: select cv/ocr source row by prev_ids, LayerNorm it with the matching
// gamma/beta, LayerNorm (pos_emb[t] + type_emb[type]) with emb gamma/beta,
// and write the sum. Both LNs share one fused block reduction (4 partial sums).
__global__ __launch_bounds__(kBlock) void prev_embed_fused(
    const float* __restrict__ cv,      // [V, H]
    const float* __restrict__ ocr,     // [B, N, H]
    const int*   __restrict__ ids,     // [B, T]
    const float* __restrict__ cv_g, const float* __restrict__ cv_b,
    const float* __restrict__ ocr_g, const float* __restrict__ ocr_b,
    const float* __restrict__ pos,     // [T, H]
    const float* __restrict__ type_emb,// [2, H]
    const float* __restrict__ emb_g, const float* __restrict__ emb_b,
    float* __restrict__ out,           // [B, T, H]
    int V, int N, int T)
{
    const int bt  = blockIdx.x;       // b*T + t
    const int t   = bt % T;
    const int b   = bt / T;
    const int tid = threadIdx.x;

    // Source-row select (wave-uniform within the block: one id per block).
    const int id = ids[bt];
    const float* grow;
    const float* gamma;
    const float* beta;
    if (id >= V) {
        int oi = id - V;
        oi = oi < 0 ? 0 : (oi > N - 1 ? N - 1 : oi);
        grow  = ocr + ((size_t)b * N + oi) * kH;
        gamma = ocr_g; beta = ocr_b;
    } else {
        int ci = id < 0 ? 0 : (id > V - 1 ? V - 1 : id);
        grow  = cv + (size_t)ci * kH;
        gamma = cv_g; beta = cv_b;
    }
    const float* trow = type_emb + ((t >= V) ? kH : 0); // faithful; always row 0 here
    const float* prow = pos + (size_t)t * kH;

    // Load both rows into registers; accumulate 4 partials in one pass.
    float x[kPer], p[kPer];
    float4 acc = make_float4(0.f, 0.f, 0.f, 0.f);
#pragma unroll
    for (int k = 0; k < kPer; ++k) {
        const int i = tid + k * kBlock;   // coalesced: lane i reads element i
        const float xv = grow[i];
        const float pv = prow[i] + trow[i];
        x[k] = xv; p[k] = pv;
        acc.x += xv; acc.y += xv * xv;
        acc.z += pv; acc.w += pv * pv;
    }

    // Wave-64 butterfly reduce, then cross-wave via LDS (4 waves).
#pragma unroll
    for (int off = 32; off >= 1; off >>= 1) {
        acc.x += __shfl_xor(acc.x, off);
        acc.y += __shfl_xor(acc.y, off);
        acc.z += __shfl_xor(acc.z, off);
        acc.w += __shfl_xor(acc.w, off);
    }
    __shared__ float4 sred[kBlock / 64];
    const int wid = tid >> 6;
    if ((tid & 63) == 0) sred[wid] = acc;
    __syncthreads();
    float4 tot = sred[0];
#pragma unroll
    for (int w = 1; w < kBlock / 64; ++w) {
        const float4 s = sred[w];
        tot.x += s.x; tot.y += s.y; tot.z += s.z; tot.w += s.w;
    }

    const float invH = 1.0f / (float)kH;
    const float mux = tot.x * invH;
    const float rsx = rsqrtf(fmaxf(tot.y * invH - mux * mux, 0.f) + LN_EPS);
    const float mup = tot.z * invH;
    const float rsp = rsqrtf(fmaxf(tot.w * invH - mup * mup, 0.f) + LN_EPS);

    float* orow = out + (size_t)bt * kH;
#pragma unroll
    for (int k = 0; k < kPer; ++k) {
        const int i = tid + k * kBlock;
        const float xn = (x[k] - mux) * rsx * gamma[i] + beta[i];
        const float pn = (p[k] - mup) * rsp * emb_g[i] + emb_b[i];
        orow[i] = xn + pn;
    }
}

extern "C" void kernel_launch(void* const* d_in, const int* in_sizes, int n_in,
                              void* d_out, int out_size, void* d_ws, size_t ws_size,
                              hipStream_t stream) {
    const float* cv    = (const float*)d_in[0];
    const float* ocr   = (const float*)d_in[1];
    const int*   ids   = (const int*)d_in[2];
    const float* cv_g  = (const float*)d_in[3];
    const float* cv_b  = (const float*)d_in[4];
    const float* ocr_g = (const float*)d_in[5];
    const float* ocr_b = (const float*)d_in[6];
    const float* pos   = (const float*)d_in[7];
    const float* typ   = (const float*)d_in[8];
    const float* emb_g = (const float*)d_in[9];
    const float* emb_b = (const float*)d_in[10];
    float* out = (float*)d_out;

    const int H  = in_sizes[3];          // 768 (gamma length)
    const int V  = in_sizes[0] / H;      // 32000
    const int T  = in_sizes[7] / H;      // 128
    const int BT = in_sizes[2];          // B*T = 2048
    const int B  = BT / T;               // 16
    const int N  = in_sizes[1] / (B * H);// 50
    (void)out_size; (void)d_ws; (void)ws_size; (void)n_in;

    prev_embed_fused<<<BT, kBlock, 0, stream>>>(
        cv, ocr, ids, cv_g, cv_b, ocr_g, ocr_b, pos, typ, emb_g, emb_b,
        out, V, N, T);
}

// Round 2
// 143.027 us; speedup vs baseline: 1.0011x; 1.0011x over previous
//
#include <hip/hip_runtime.h>

#define LN_EPS 1e-5f

constexpr int kH   = 768;                 // hidden dim
constexpr int kRPB = 4;                   // rows (waves) per block
constexpr int kBlock = 64 * kRPB;         // 256 threads
constexpr int kVec = kH / (64 * 4);       // 3 float4 per lane per row

// One WAVE per output row (b,t): 64 lanes x 3 float4 = 768 floats.
// Dual LayerNorm (gathered row + pos/type row) with a single 4-partial
// wave butterfly reduction. No LDS, no __syncthreads.
__global__ __launch_bounds__(kBlock) void prev_embed_fused(
    const float* __restrict__ cv,       // [V, H]
    const float* __restrict__ ocr,      // [B, N, H]
    const int*   __restrict__ ids,      // [B, T]
    const float* __restrict__ cv_g, const float* __restrict__ cv_b,
    const float* __restrict__ ocr_g, const float* __restrict__ ocr_b,
    const float* __restrict__ pos,      // [T, H]
    const float* __restrict__ type_emb, // [2, H]
    const float* __restrict__ emb_g, const float* __restrict__ emb_b,
    float* __restrict__ out,            // [B, T, H]
    int V, int N, int T)
{
    const int wave = threadIdx.x >> 6;
    const int lane = threadIdx.x & 63;
    const int bt   = blockIdx.x * kRPB + wave;   // BT divisible by kRPB (2048)
    const int t    = bt % T;
    const int b    = bt / T;

    // Row select (wave-uniform: one id per wave; scalar-cached broadcast).
    const int id = ids[bt];
    const float* grow;
    const float* gamma;
    const float* beta;
    if (id >= V) {
        int oi = id - V;
        oi = oi < 0 ? 0 : (oi > N - 1 ? N - 1 : oi);
        grow  = ocr + ((size_t)b * N + oi) * kH;
        gamma = ocr_g; beta = ocr_b;
    } else {
        int ci = id < 0 ? 0 : (id > V - 1 ? V - 1 : id);
        grow  = cv + (size_t)ci * kH;
        gamma = cv_g; beta = cv_b;
    }
    const float4* grow4 = (const float4*)grow;
    const float4* prow4 = (const float4*)(pos + (size_t)t * kH);
    const float4* trow4 = (const float4*)(type_emb + ((t >= V) ? kH : 0));

    // Load both rows as float4; accumulate 4 partials in one pass.
    float4 x[kVec], p[kVec];
    float sx = 0.f, sxx = 0.f, sp = 0.f, spp = 0.f;
#pragma unroll
    for (int k = 0; k < kVec; ++k) {
        const int i = lane + k * 64;          // coalesced float4 index
        float4 xv = grow4[i];
        float4 pv = prow4[i];
        const float4 tv = trow4[i];
        pv.x += tv.x; pv.y += tv.y; pv.z += tv.z; pv.w += tv.w;
        x[k] = xv; p[k] = pv;
        sx  += xv.x + xv.y + xv.z + xv.w;
        sxx += xv.x * xv.x + xv.y * xv.y + xv.z * xv.z + xv.w * xv.w;
        sp  += pv.x + pv.y + pv.z + pv.w;
        spp += pv.x * pv.x + pv.y * pv.y + pv.z * pv.z + pv.w * pv.w;
    }

    // 64-lane butterfly reduction of the 4 partials (6 steps, no LDS).
#pragma unroll
    for (int off = 32; off >= 1; off >>= 1) {
        sx  += __shfl_xor(sx,  off);
        sxx += __shfl_xor(sxx, off);
        sp  += __shfl_xor(sp,  off);
        spp += __shfl_xor(spp, off);
    }

    const float invH = 1.0f / (float)kH;
    const float mux = sx * invH;
    const float rsx = rsqrtf(fmaxf(sxx * invH - mux * mux, 0.f) + LN_EPS);
    const float mup = sp * invH;
    const float rsp = rsqrtf(fmaxf(spp * invH - mup * mup, 0.f) + LN_EPS);

    const float4* g4  = (const float4*)gamma;
    const float4* b4  = (const float4*)beta;
    const float4* eg4 = (const float4*)emb_g;
    const float4* eb4 = (const float4*)emb_b;
    float4* orow4 = (float4*)(out + (size_t)bt * kH);
#pragma unroll
    for (int k = 0; k < kVec; ++k) {
        const int i = lane + k * 64;
        const float4 gv = g4[i],  bv = b4[i];
        const float4 ev = eg4[i], fv = eb4[i];
        float4 o;
        o.x = (x[k].x - mux) * rsx * gv.x + bv.x + (p[k].x - mup) * rsp * ev.x + fv.x;
        o.y = (x[k].y - mux) * rsx * gv.y + bv.y + (p[k].y - mup) * rsp * ev.y + fv.y;
        o.z = (x[k].z - mux) * rsx * gv.z + bv.z + (p[k].z - mup) * rsp * ev.z + fv.z;
        o.w = (x[k].w - mux) * rsx * gv.w + bv.w + (p[k].w - mup) * rsp * ev.w + fv.w;
        orow4[i] = o;
    }
}

extern "C" void kernel_launch(void* const* d_in, const int* in_sizes, int n_in,
                              void* d_out, int out_size, void* d_ws, size_t ws_size,
                              hipStream_t stream) {
    const float* cv    = (const float*)d_in[0];
    const float* ocr   = (const float*)d_in[1];
    const int*   ids   = (const int*)d_in[2];
    const float* cv_g  = (const float*)d_in[3];
    const float* cv_b  = (const float*)d_in[4];
    const float* ocr_g = (const float*)d_in[5];
    const float* ocr_b = (const float*)d_in[6];
    const float* pos   = (const float*)d_in[7];
    const float* typ   = (const float*)d_in[8];
    const float* emb_g = (const float*)d_in[9];
    const float* emb_b = (const float*)d_in[10];
    float* out = (float*)d_out;

    const int H  = in_sizes[3];           // 768
    const int V  = in_sizes[0] / H;       // 32000
    const int T  = in_sizes[7] / H;       // 128
    const int BT = in_sizes[2];           // B*T = 2048
    const int B  = BT / T;                // 16
    const int N  = in_sizes[1] / (B * H); // 50
    (void)out_size; (void)d_ws; (void)ws_size; (void)n_in;

    prev_embed_fused<<<BT / kRPB, kBlock, 0, stream>>>(
        cv, ocr, ids, cv_g, cv_b, ocr_g, ocr_b, pos, typ, emb_g, emb_b,
        out, V, N, T);
}